// Round 2
// baseline (1078.348 us; speedup 1.0000x reference)
//
#include <hip/hip_runtime.h>
#include <hip/hip_bf16.h>
#include <stdint.h>

// ---- problem constants ----
#define NB   65536      // batch points
#define NC   2
#define NV   3
#define ND   64
#define NK   1024       // codebook entries
#define NS   4
#define NH   1024
#define NL   5
#define NF   25
#define NIN  102
#define K0P  128        // padded layer-0 K

typedef __bf16 bf16x8 __attribute__((ext_vector_type(8)));
typedef float  f32x4  __attribute__((ext_vector_type(4)));

__device__ __forceinline__ void load_lds16(const void* g, void* l) {
    __builtin_amdgcn_global_load_lds(
        (const __attribute__((address_space(1))) void*)g,
        (__attribute__((address_space(3))) void*)l,
        16, 0, 0);
}

// ---------------------------------------------------------------------------
// VQ kernel: single block, 1024 threads. Replicates the reference's fp32
// sequencing for z_cur / z_q_sum / loss. Writes idxs (as float) and loss to
// d_out tail, z_q_sum (64 f32) to workspace.
// ---------------------------------------------------------------------------
__global__ __launch_bounds__(1024) void vq_kernel(
    const float* __restrict__ latents, const int* __restrict__ latent_idx,
    const float* __restrict__ codebooks, float* __restrict__ zq_out,
    float* __restrict__ out) {
    __shared__ float zcur[ND], resid[ND], zqsum[ND], ssq[ND];
    __shared__ float sD[NK];
    __shared__ int   sK[NK];
    __shared__ int   sBest;
    int t = threadIdx.x;
    const float* img = latents + (size_t)latent_idx[0] * (NS * ND);
    if (t < ND) { resid[t] = 0.f; zqsum[t] = 0.f; }
    __syncthreads();
    float lossAcc = 0.f;   // thread 0 only
    for (int s = 0; s < NS; s++) {
        if (t < ND) {
            float iv = img[s * ND + t];
            float r  = resid[t] + iv;
            resid[t] = r;
            zcur[t]  = (s == 0) ? iv : (r - zqsum[t]);
        }
        __syncthreads();
        // distance for codebook row t: zz - 2*dot + ee  (matches ref formula)
        float zz = 0.f;
        for (int d = 0; d < ND; d++) { float z = zcur[d]; zz += z * z; }
        const float* e = codebooks + ((size_t)s * NK + t) * ND;
        float dot = 0.f, ee = 0.f;
        for (int d = 0; d < ND; d++) { float ev = e[d]; dot += zcur[d] * ev; ee += ev * ev; }
        sD[t] = zz - 2.0f * dot + ee;
        sK[t] = t;
        __syncthreads();
        // tree argmin, tie -> lowest k (first-index semantics)
        for (int st = 512; st > 0; st >>= 1) {
            if (t < st) {
                float d2 = sD[t + st]; int k2 = sK[t + st];
                if (d2 < sD[t] || (d2 == sD[t] && k2 < sK[t])) { sD[t] = d2; sK[t] = k2; }
            }
            __syncthreads();
        }
        if (t == 0) { sBest = sK[0]; out[NB * NV + s] = (float)sK[0]; }
        __syncthreads();
        int best = sBest;
        const float* eb = codebooks + ((size_t)s * NK + best) * ND;
        if (t < ND) {
            float zq = eb[t];
            float d  = zq - zcur[t];
            ssq[t]   = d * d;
            zqsum[t] = zqsum[t] + (zq + (zcur[t] - zq));   // z_q_st forward (exact ref arith)
        }
        __syncthreads();
        if (t == 0) {
            float sum = 0.f;
            for (int d = 0; d < ND; d++) sum += ssq[d];
            lossAcc += 0.25f * (sum / (float)ND);
        }
        __syncthreads();
    }
    if (t < ND) zq_out[t] = zqsum[t];
    if (t == 0) out[NB * NV + NS] = lossAcc;
}

// ---------------------------------------------------------------------------
// betas fused with decoder biases: bb[l][n] = sum_d zq[d]*mod_W[l][d][n]
//                                            + mod_b[l][n] + (l==0 ? b0[n] : bh[l-1][n])
// ---------------------------------------------------------------------------
__global__ __launch_bounds__(256) void betas_kernel(
    const float* __restrict__ zq, const float* __restrict__ mod_W,
    const float* __restrict__ mod_b, const float* __restrict__ b0,
    const float* __restrict__ bh, float* __restrict__ bb) {
    int g = blockIdx.x * 256 + threadIdx.x;   // < 5120
    int l = g >> 10, n = g & 1023;
    float acc = mod_b[g];
    for (int d = 0; d < ND; d++) acc += zq[d] * mod_W[(size_t)(l * ND + d) * NH + n];
    acc += (l == 0) ? b0[n] : bh[(size_t)(l - 1) * NH + n];
    bb[g] = acc;
}

// ---------------------------------------------------------------------------
// Weight prep: fp32 [Ks][1024] -> bf16 transposed [1024][Kp] (zero-pad k>=Ks).
// 32x32 LDS tile transpose, coalesced both directions.
// ---------------------------------------------------------------------------
__global__ __launch_bounds__(256) void prep_kernel(
    const float* __restrict__ src, __bf16* __restrict__ dst, int Ks, int Kp) {
    __shared__ float tile[32][33];
    src += (size_t)blockIdx.z * Ks * NH;
    dst += (size_t)blockIdx.z * NH * Kp;
    int k0 = blockIdx.x * 32, n0 = blockIdx.y * 32;
    int tx = threadIdx.x, ty = threadIdx.y;   // (32, 8)
    for (int i = 0; i < 4; i++) {
        int k = k0 + ty + i * 8;
        int n = n0 + tx;
        tile[ty + i * 8][tx] = (k < Ks) ? src[(size_t)k * NH + n] : 0.0f;
    }
    __syncthreads();
    for (int i = 0; i < 4; i++) {
        int n = n0 + ty + i * 8;
        int k = k0 + tx;
        dst[(size_t)n * Kp + k] = (__bf16)tile[tx][ty + i * 8];
    }
}

// ---------------------------------------------------------------------------
// Positional encoding for a batch chunk -> bf16 [Bc][128], zero-pad 102..127.
// pe layout: [c0, c1, then f-major groups of (sin c0, sin c1, cos c0, cos c1)]
// ---------------------------------------------------------------------------
__global__ __launch_bounds__(256) void pe_kernel(
    const float* __restrict__ coords, __bf16* __restrict__ pe) {
    int g = blockIdx.x * 256 + threadIdx.x;   // < Bc*128
    int m = g >> 7, k = g & 127;
    float v = 0.0f;
    if (k < 2) {
        v = coords[m * 2 + k];
    } else if (k < NIN) {
        int u = k - 2;
        int f = u >> 2, r = u & 3;
        float c = coords[m * 2 + (r & 1)];
        // float32(pi) * 2^f is exact; then one fp32 multiply (matches numpy)
        float a = c * __builtin_ldexpf(3.14159274101257324f, f);
        v = (r < 2) ? sinf(a) : cosf(a);
    }
    pe[g] = (__bf16)v;
}

// ---------------------------------------------------------------------------
// MFMA GEMM: O[M][1024] = relu(A[M][K] @ W^T[1024][K] + bb[n]), bf16 in/out,
// fp32 accumulate. 128x128 tile, BK=32, 4 waves (2x2), 16x16x32 bf16 MFMA.
// LDS in 16B chunks with XOR swizzle c^((row>>1)&3): frag ds_read_b128 are
// 2-way-bank-aliased only (free per m136). Staging: global_load_lds width=16.
// ---------------------------------------------------------------------------
__global__ __launch_bounds__(256, 2) void gemm_kernel(
    const __bf16* __restrict__ A, const __bf16* __restrict__ W,
    const float* __restrict__ bb, __bf16* __restrict__ O, int K) {
    __shared__ __align__(16) __bf16 sA[128 * 32];
    __shared__ __align__(16) __bf16 sW[128 * 32];
    int t    = threadIdx.x;
    int bn   = blockIdx.x;            // 0..7      (N)
    int bm   = blockIdx.y;            // 0..Bc/128 (M)
    int lane = t & 63, wv = t >> 6;
    int wm   = wv >> 1, wn = wv & 1;
    int q    = lane >> 4, r16 = lane & 15;

    f32x4 acc[4][4];
    f32x4 zero = {0.f, 0.f, 0.f, 0.f};
    for (int i = 0; i < 4; i++)
        for (int j = 0; j < 4; j++) acc[i][j] = zero;

    for (int k0 = 0; k0 < K; k0 += 32) {
        // stage 8KB A-tile + 8KB W-tile: 512 16B-chunks each, 2 per thread;
        // each wave's LDS dests are wave-uniform base + lane*16 (m104 rule).
#pragma unroll
        for (int p = 0; p < 2; p++) {
            int i  = p * 256 + t;
            int r  = i >> 2;
            int cg = (i & 3) ^ ((r >> 1) & 3);     // swizzled source chunk
            const __bf16* gA = A + ((size_t)(bm * 128 + r) * K + (size_t)(k0 + cg * 8));
            load_lds16((const void*)gA, (void*)((char*)sA + i * 16));
            const __bf16* gW = W + ((size_t)(bn * 128 + r) * K + (size_t)(k0 + cg * 8));
            load_lds16((const void*)gW, (void*)((char*)sW + i * 16));
        }
        __syncthreads();

        bf16x8 af[4], bfr[4];
#pragma unroll
        for (int i = 0; i < 4; i++) {
            int rowA = wm * 64 + i * 16 + r16;
            int chA  = rowA * 4 + (q ^ ((rowA >> 1) & 3));
            af[i]    = *(const bf16x8*)(sA + chA * 8);
            int rowB = wn * 64 + i * 16 + r16;
            int chB  = rowB * 4 + (q ^ ((rowB >> 1) & 3));
            bfr[i]   = *(const bf16x8*)(sW + chB * 8);
        }
#pragma unroll
        for (int i = 0; i < 4; i++)
#pragma unroll
            for (int j = 0; j < 4; j++)
                acc[i][j] = __builtin_amdgcn_mfma_f32_16x16x32_bf16(af[i], bfr[j], acc[i][j], 0, 0, 0);
        __syncthreads();
    }

    // epilogue: C/D layout col=lane&15, row=(lane>>4)*4+reg
#pragma unroll
    for (int i = 0; i < 4; i++) {
        int mbase = bm * 128 + wm * 64 + i * 16 + q * 4;
#pragma unroll
        for (int j = 0; j < 4; j++) {
            int n = bn * 128 + wn * 64 + j * 16 + r16;
            float bias = bb[n];
#pragma unroll
            for (int r = 0; r < 4; r++) {
                float val = acc[i][j][r] + bias;
                val = fmaxf(val, 0.0f);
                O[(size_t)(mbase + r) * NH + n] = (__bf16)val;
            }
        }
    }
}

// ---------------------------------------------------------------------------
// Output layer: one wave per point, values[m][v] = h[m]@Wout[:,v] + bout[v]
// ---------------------------------------------------------------------------
__global__ __launch_bounds__(256) void out_kernel(
    const __bf16* __restrict__ h, const float* __restrict__ Wout,
    const float* __restrict__ bout, float* __restrict__ out) {
    int wid  = (blockIdx.x * 256 + threadIdx.x) >> 6;   // point index in chunk
    int lane = threadIdx.x & 63;
    const __bf16* row = h + (size_t)wid * NH;
    float s0 = 0.f, s1 = 0.f, s2 = 0.f;
#pragma unroll
    for (int half = 0; half < 2; half++) {
        int k0 = half * 512 + lane * 8;
        bf16x8 v8 = *(const bf16x8*)(row + k0);
#pragma unroll
        for (int j = 0; j < 8; j++) {
            float hv = (float)v8[j];
            const float* w = Wout + (size_t)(k0 + j) * NV;
            s0 += hv * w[0]; s1 += hv * w[1]; s2 += hv * w[2];
        }
    }
    for (int off = 32; off > 0; off >>= 1) {
        s0 += __shfl_down(s0, off);
        s1 += __shfl_down(s1, off);
        s2 += __shfl_down(s2, off);
    }
    if (lane == 0) {
        out[(size_t)wid * NV + 0] = s0 + bout[0];
        out[(size_t)wid * NV + 1] = s1 + bout[1];
        out[(size_t)wid * NV + 2] = s2 + bout[2];
    }
}

// ---------------------------------------------------------------------------
extern "C" void kernel_launch(void* const* d_in, const int* in_sizes, int n_in,
                              void* d_out, int out_size, void* d_ws, size_t ws_size,
                              hipStream_t stream) {
    const float* coords     = (const float*)d_in[0];
    const int*   latent_idx = (const int*)d_in[1];
    const float* latents    = (const float*)d_in[2];
    const float* codebooks  = (const float*)d_in[3];
    const float* mod_W      = (const float*)d_in[4];
    const float* mod_b      = (const float*)d_in[5];
    const float* dec_W0     = (const float*)d_in[6];
    const float* dec_b0     = (const float*)d_in[7];
    const float* dec_Wh     = (const float*)d_in[8];
    const float* dec_bh     = (const float*)d_in[9];
    const float* dec_Wout   = (const float*)d_in[10];
    const float* dec_bout   = (const float*)d_in[11];
    float* out = (float*)d_out;

    // ---- workspace layout (fixed part ~8.67 MB) ----
    char* wsb = (char*)d_ws;
    float*  zq  = (float*)(wsb + 0);                       //      256 B
    float*  bb  = (float*)(wsb + 256);                     //   20,480 B
    __bf16* W0T = (__bf16*)(wsb + 20736);                  //  262,144 B  [1024][128]
    __bf16* WhT = (__bf16*)(wsb + 282880);                 // 8,388,608 B [4][1024][1024]
    const size_t fixed_end = 8671488;

    // ---- adaptive batch chunk: 2 ping-pong bf16 activation buffers of
    //      Bc*1024 elements each. Bc capped at 16384 (ws ~75.8 MB) and halved
    //      until the layout fits ws_size. Deterministic in ws_size ->
    //      identical launch sequence every call (graph-capture safe).
    int Bc = 16384;
    while (Bc > 256 && fixed_end + 2 * (size_t)Bc * NH * sizeof(__bf16) > ws_size)
        Bc >>= 1;

    __bf16* hA = (__bf16*)(wsb + fixed_end);               // [Bc][1024]
    __bf16* hB = hA + (size_t)Bc * NH;                     // [Bc][1024]
    __bf16* pe = hB;   // pe [Bc][128] aliases hB (dead before layer-1 writes hB)

    // ---- one-time (per call) small kernels ----
    vq_kernel<<<1, 1024, 0, stream>>>(latents, latent_idx, codebooks, zq, out);
    betas_kernel<<<20, 256, 0, stream>>>(zq, mod_W, mod_b, dec_b0, dec_bh, bb);
    prep_kernel<<<dim3(4, 32, 1), dim3(32, 8), 0, stream>>>(dec_W0, W0T, NIN, K0P);
    prep_kernel<<<dim3(32, 32, 4), dim3(32, 8), 0, stream>>>(dec_Wh, WhT, NH, NH);

    // ---- chunked 5-layer MLP ----
    for (int c0 = 0; c0 < NB; c0 += Bc) {
        pe_kernel<<<(Bc * 128) / 256, 256, 0, stream>>>(coords + (size_t)c0 * NC, pe);
        // layer 0: pe [Bc][128] @ W0T -> hA
        gemm_kernel<<<dim3(8, Bc / 128), 256, 0, stream>>>(pe, W0T, bb + 0 * NH, hA, K0P);
        // hidden layers 1..4
        gemm_kernel<<<dim3(8, Bc / 128), 256, 0, stream>>>(hA, WhT + 0 * (size_t)NH * NH, bb + 1 * NH, hB, NH);
        gemm_kernel<<<dim3(8, Bc / 128), 256, 0, stream>>>(hB, WhT + 1 * (size_t)NH * NH, bb + 2 * NH, hA, NH);
        gemm_kernel<<<dim3(8, Bc / 128), 256, 0, stream>>>(hA, WhT + 2 * (size_t)NH * NH, bb + 3 * NH, hB, NH);
        gemm_kernel<<<dim3(8, Bc / 128), 256, 0, stream>>>(hB, WhT + 3 * (size_t)NH * NH, bb + 4 * NH, hA, NH);
        out_kernel<<<Bc / 4, 256, 0, stream>>>(hA, dec_Wout, dec_bout, out + (size_t)c0 * NV);
    }
}